// Round 8
// baseline (354.788 us; speedup 1.0000x reference)
//
#include <hip/hip_runtime.h>
#include <stdint.h>

// Problem constants (fixed by reference setup_inputs)
constexpr int N = 65536, K = 512, F = 512;
constexpr float ASCALE = 127.0f / 3.0f;   // activation scale (fixed bound 3.0)

typedef short frag8 __attribute__((ext_vector_type(8)));   // 8 bf16 = 4 VGPRs
typedef float floatx4 __attribute__((ext_vector_type(4))); // MFMA C/D

// round-half-even, clip to [-127,127], truncate fp32->bf16 (exact for ints <= 127)
__device__ __forceinline__ unsigned short quant_bf16(float v, float s) {
    float q = rintf(v * s);
    q = fminf(fmaxf(q, -127.0f), 127.0f);
    union { float f; unsigned int u; } cvt; cvt.f = q;
    return (unsigned short)(cvt.u >> 16);
}

// quantize 8 consecutive floats -> packed 8x bf16 (uint4)
__device__ __forceinline__ uint4 quant8(const float4& a, const float4& b) {
    unsigned int q0 = quant_bf16(a.x, ASCALE), q1 = quant_bf16(a.y, ASCALE);
    unsigned int q2 = quant_bf16(a.z, ASCALE), q3 = quant_bf16(a.w, ASCALE);
    unsigned int q4 = quant_bf16(b.x, ASCALE), q5 = quant_bf16(b.y, ASCALE);
    unsigned int q6 = quant_bf16(b.z, ASCALE), q7 = quant_bf16(b.w, ASCALE);
    uint4 r;
    r.x = q0 | (q1 << 16); r.y = q2 | (q3 << 16);
    r.z = q4 | (q5 << 16); r.w = q6 | (q7 << 16);
    return r;
}

// --- Phase 0: streaming activation fake-quant: x f32 -> x_q bf16 ---
// 16 elems/thread: 64B/lane reads, 32B/lane writes. Cached stores keep x_q
// L3-resident for the gemm (r6: FETCH showed ~40% L3 hit on x_q).
__global__ __launch_bounds__(256)
void quant_x_kernel(const float* __restrict__ x, unsigned short* __restrict__ xq) {
    size_t idx = ((size_t)blockIdx.x * 256 + threadIdx.x) * 16;
    float4 a0 = *(const float4*)(x + idx);
    float4 a1 = *(const float4*)(x + idx + 4);
    float4 a2 = *(const float4*)(x + idx + 8);
    float4 a3 = *(const float4*)(x + idx + 12);
    *(uint4*)(xq + idx)     = quant8(a0, a1);
    *(uint4*)(xq + idx + 8) = quant8(a2, a3);
}

// --- Phase 1: per-output-channel weight quant -> wT[f][k] (bf16), dscale[f] ---
// (r3/r6-verified) 64 blocks x 512 threads; block owns 8 f-cols.
__global__ __launch_bounds__(512)
void quant_w_kernel(const float* __restrict__ kern,
                    unsigned short* __restrict__ wT,
                    float* __restrict__ dscale) {
    constexpr int TF = 8;
    constexpr int LDQ = K + 8;
    __shared__ float pwmax[8][TF];
    __shared__ float wscl[TF];
    __shared__ unsigned short q_t[TF * LDQ];

    const int t = threadIdx.x;
    const int lane = t & 63;
    const int wave = t >> 6;
    const int fl = t & 7;
    const int kc = t >> 3;
    const int f0 = blockIdx.x * TF;

    float v[8];
    const float* kp = kern + (size_t)(kc * 8) * F + f0 + fl;
    #pragma unroll
    for (int j = 0; j < 8; ++j) v[j] = kp[(size_t)j * F];

    float mx = 0.0f;
    #pragma unroll
    for (int j = 0; j < 8; ++j) mx = fmaxf(mx, fabsf(v[j]));
    #pragma unroll
    for (int d = 8; d < 64; d <<= 1) mx = fmaxf(mx, __shfl_xor(mx, d, 64));
    if (lane < 8) pwmax[wave][fl] = mx;
    __syncthreads();

    if (t < TF) {
        float m = 0.0f;
        #pragma unroll
        for (int w = 0; w < 8; ++w) m = fmaxf(m, pwmax[w][t]);
        m = fmaxf(m, 1e-7f);
        wscl[t] = 127.0f / m;
        dscale[f0 + t] = 3.0f * m / 16129.0f;
    }
    __syncthreads();

    const float ws = wscl[fl];
    {
        unsigned int q0 = quant_bf16(v[0], ws), q1 = quant_bf16(v[1], ws);
        unsigned int q2 = quant_bf16(v[2], ws), q3 = quant_bf16(v[3], ws);
        unsigned int q4 = quant_bf16(v[4], ws), q5 = quant_bf16(v[5], ws);
        unsigned int q6 = quant_bf16(v[6], ws), q7 = quant_bf16(v[7], ws);
        uint4 pk;
        pk.x = q0 | (q1 << 16); pk.y = q2 | (q3 << 16);
        pk.z = q4 | (q5 << 16); pk.w = q6 | (q7 << 16);
        *(uint4*)&q_t[fl * LDQ + kc * 8] = pk;
    }
    __syncthreads();

    const int r = t >> 6;
    const int c = t & 63;
    *(uint4*)&wT[(size_t)(f0 + r) * K + c * 8] =
        *(const uint4*)&q_t[r * LDQ + c * 8];
}

// --- Phase 2: persistent pipelined bf16 MFMA GEMM ---
// 512 blocks (2/CU) x 512 threads; BM=32; each block owns 4 consecutive tiles.
// Double-buffered LDS (2 x 32 KB). Per tile: compute 16 k-subtiles from
// buf[cur]; at gk=15 (the only subtile with NO pending B-load wait -- any
// later vmcnt wait would FIFO-drain the DMA) issue the next tile's DMA burst
// into buf[cur^1]; epilogue stores; one barrier (drains DMA); reload B(0).
// DMA overlaps gk15 MFMAs + epilogue; co-resident block covers the rest.
// A-path: global_load_lds w=16, linear LDS dest + XOR-swizzled global source,
// same XOR on ds_read (rule #21; r6-verified correct).
__global__ __launch_bounds__(512, 4)
void gemm_kernel(const unsigned short* __restrict__ xq,
                 const unsigned short* __restrict__ wT,
                 const float* __restrict__ dscale,
                 const float* __restrict__ bias,
                 float* __restrict__ out) {
    constexpr int BM = 32, TPB = 4;
    __shared__ unsigned short As[2][BM * K];   // 2 x 32768 B

    const int t = threadIdx.x;
    const int blk = blockIdx.x;
    const int lane = t & 63;
    const int wave = t >> 6;     // 0..7
    const int m16 = lane & 15;
    const int quad = lane >> 4;

    floatx4 acc[2][4];
    #pragma unroll
    for (int i = 0; i < 2; ++i)
        #pragma unroll
        for (int j = 0; j < 4; ++j)
            acc[i][j] = (floatx4){0.f, 0.f, 0.f, 0.f};

    // per-lane B fragment base: wT[(wave*64 + m16)][quad*8]
    const unsigned short* bp = wT + (size_t)(wave * 64 + m16) * K + quad * 8;

    // per-thread epilogue constants (loaded once)
    float dsv[4], bvv[4];
    #pragma unroll
    for (int nt = 0; nt < 4; ++nt) {
        int col = wave * 64 + nt * 16 + m16;
        dsv[nt] = dscale[col];
        bvv[nt] = bias[col];
    }

    // ---- prologue: DMA tile 0 into buf 0; load B(0) ----
    #pragma unroll
    for (int i = 0; i < 4; ++i) {
        const int r = wave * 4 + i;
        const unsigned short* src =
            xq + (size_t)(blk * TPB) * BM * K + (size_t)r * K + ((lane ^ (r & 7)) * 8);
        __builtin_amdgcn_global_load_lds(
            (const __attribute__((address_space(1))) unsigned int*)src,
            (__attribute__((address_space(3))) unsigned int*)&As[0][r * K],
            16, 0, 0);
    }
    frag8 bcur[4], bnext[4];
    #pragma unroll
    for (int nt = 0; nt < 4; ++nt)
        bcur[nt] = *(const frag8*)(bp + (size_t)nt * 16 * K);

    __syncthreads();   // drains prologue DMA + B(0)

    const int cswz = m16 & 7;   // read-side XOR key (row&7 == m16&7 since 16|mt*16)

    for (int tt = 0; tt < TPB; ++tt) {
        const int cur = tt & 1;

        #pragma unroll
        for (int gk = 0; gk < 16; ++gk) {
            if (gk < 15) {   // prefetch next B subtile (L2-resident wT)
                #pragma unroll
                for (int nt = 0; nt < 4; ++nt)
                    bnext[nt] = *(const frag8*)(bp + (size_t)nt * 16 * K + (gk + 1) * 32);
            }
            if (gk == 15 && tt + 1 < TPB) {
                // safe DMA point: no B-load wait after this until the barrier
                __builtin_amdgcn_sched_barrier(0);
                #pragma unroll
                for (int i = 0; i < 4; ++i) {
                    const int r = wave * 4 + i;
                    const unsigned short* src =
                        xq + (size_t)(blk * TPB + tt + 1) * BM * K + (size_t)r * K
                           + ((lane ^ (r & 7)) * 8);
                    __builtin_amdgcn_global_load_lds(
                        (const __attribute__((address_space(1))) unsigned int*)src,
                        (__attribute__((address_space(3))) unsigned int*)&As[cur ^ 1][r * K],
                        16, 0, 0);
                }
                __builtin_amdgcn_sched_barrier(0);
            }
            frag8 af[2];
            const int c = (gk * 4 + quad) ^ cswz;
            #pragma unroll
            for (int mt = 0; mt < 2; ++mt)
                af[mt] = *(const frag8*)&As[cur][(mt * 16 + m16) * K + c * 8];
            #pragma unroll
            for (int nt = 0; nt < 4; ++nt)
                #pragma unroll
                for (int mt = 0; mt < 2; ++mt)
                    acc[mt][nt] = __builtin_amdgcn_mfma_f32_16x16x32_bf16(
                        af[mt], bcur[nt], acc[mt][nt], 0, 0, 0);
            if (gk < 15) {
                #pragma unroll
                for (int nt = 0; nt < 4; ++nt) bcur[nt] = bnext[nt];
            }
        }

        // ---- epilogue for tile tt (stores overlap the in-flight DMA) ----
        const size_t trow = (size_t)(blk * TPB + tt) * BM;
        #pragma unroll
        for (int nt = 0; nt < 4; ++nt) {
            const int col = wave * 64 + nt * 16 + m16;
            #pragma unroll
            for (int mt = 0; mt < 2; ++mt) {
                const size_t row = trow + mt * 16 + quad * 4;
                #pragma unroll
                for (int r = 0; r < 4; ++r)
                    __builtin_nontemporal_store(acc[mt][nt][r] * dsv[nt] + bvv[nt],
                                                &out[(row + r) * F + col]);
            }
        }
        #pragma unroll
        for (int i = 0; i < 2; ++i)
            #pragma unroll
            for (int j = 0; j < 4; ++j)
                acc[i][j] = (floatx4){0.f, 0.f, 0.f, 0.f};

        if (tt + 1 < TPB) {
            __syncthreads();   // drains DMA (and stores); buf[cur^1] now valid
            #pragma unroll
            for (int nt = 0; nt < 4; ++nt)   // reload B(0); wait lands in gk0, post-barrier
                bcur[nt] = *(const frag8*)(bp + (size_t)nt * 16 * K);
        }
    }
}

extern "C" void kernel_launch(void* const* d_in, const int* in_sizes, int n_in,
                              void* d_out, int out_size, void* d_ws, size_t ws_size,
                              hipStream_t stream) {
    const float* x    = (const float*)d_in[0];
    const float* kern = (const float*)d_in[1];
    const float* bias = (const float*)d_in[2];
    float* out = (float*)d_out;

    unsigned short* wT = (unsigned short*)d_ws;                       // 512 KB
    float* dscale = (float*)((char*)d_ws + (size_t)K * F * sizeof(unsigned short));
    unsigned short* xq = (unsigned short*)((char*)d_ws + (size_t)K * F * 2 + F * 4);
    // xq: 65536*512 bf16 = 64 MB workspace

    quant_x_kernel<<<(size_t)N * K / 16 / 256, 256, 0, stream>>>(x, xq);
    quant_w_kernel<<<F / 8, 512, 0, stream>>>(kern, wT, dscale);
    gemm_kernel<<<512, 512, 0, stream>>>(xq, wT, dscale, bias, out);
}

// Round 10
// 296.010 us; speedup vs baseline: 1.1986x; 1.1986x over previous
//
#include <hip/hip_runtime.h>
#include <stdint.h>

// Problem constants (fixed by reference setup_inputs)
constexpr int N = 65536, K = 512, F = 512;
constexpr float ASCALE = 127.0f / 3.0f;   // activation scale (fixed bound 3.0)

typedef int  int4v  __attribute__((ext_vector_type(4)));   // 4 dwords = 16 int8 / i32x4 acc

// round-half-even then clip to [-127,127] (reference order: round, then clip)
__device__ __forceinline__ int quant_i(float v, float s) {
    float q = rintf(v * s);
    q = fminf(fmaxf(q, -127.0f), 127.0f);
    return (int)q;
}

__device__ __forceinline__ unsigned int pack4(const float* v, float s) {
    unsigned int b0 = (unsigned int)quant_i(v[0], s) & 255u;
    unsigned int b1 = (unsigned int)quant_i(v[1], s) & 255u;
    unsigned int b2 = (unsigned int)quant_i(v[2], s) & 255u;
    unsigned int b3 = (unsigned int)quant_i(v[3], s) & 255u;
    return b0 | (b1 << 8) | (b2 << 16) | (b3 << 24);
}

// --- Phase 0: streaming activation fake-quant: x f32 -> x_q int8 ---
// 16 elems/thread: 64B/lane read, 16B/lane write. 128 MB R + 32 MB W.
__global__ __launch_bounds__(256)
void quant_x_kernel(const float* __restrict__ x, unsigned char* __restrict__ xq) {
    size_t idx = ((size_t)blockIdx.x * 256 + threadIdx.x) * 16;
    float v[16];
    *(float4*)(v + 0)  = *(const float4*)(x + idx);
    *(float4*)(v + 4)  = *(const float4*)(x + idx + 4);
    *(float4*)(v + 8)  = *(const float4*)(x + idx + 8);
    *(float4*)(v + 12) = *(const float4*)(x + idx + 12);
    uint4 p;
    p.x = pack4(v + 0,  ASCALE);
    p.y = pack4(v + 4,  ASCALE);
    p.z = pack4(v + 8,  ASCALE);
    p.w = pack4(v + 12, ASCALE);
    *(uint4*)(xq + idx) = p;
}

// --- Phase 1: per-output-channel weight quant -> wT8[f][k] (int8), dscale[f] ---
// 64 blocks x 512 threads; block owns 8 f-cols (r3/r6-verified structure).
__global__ __launch_bounds__(512)
void quant_w_kernel(const float* __restrict__ kern,
                    unsigned char* __restrict__ wT8,
                    float* __restrict__ dscale) {
    constexpr int TF = 8;
    constexpr int LDQ = K + 16;               // 528 B row stride (16B-aligned)
    __shared__ float pwmax[8][TF];
    __shared__ float wscl[TF];
    __shared__ unsigned char q_t[TF * LDQ];   // 8 x 528 int8

    const int t = threadIdx.x;
    const int lane = t & 63;
    const int wave = t >> 6;
    const int fl = t & 7;
    const int kc = t >> 3;          // 0..63
    const int f0 = blockIdx.x * TF;

    float v[8];
    const float* kp = kern + (size_t)(kc * 8) * F + f0 + fl;
    #pragma unroll
    for (int j = 0; j < 8; ++j) v[j] = kp[(size_t)j * F];

    float mx = 0.0f;
    #pragma unroll
    for (int j = 0; j < 8; ++j) mx = fmaxf(mx, fabsf(v[j]));
    #pragma unroll
    for (int d = 8; d < 64; d <<= 1) mx = fmaxf(mx, __shfl_xor(mx, d, 64));
    if (lane < 8) pwmax[wave][fl] = mx;
    __syncthreads();

    if (t < TF) {
        float m = 0.0f;
        #pragma unroll
        for (int w = 0; w < 8; ++w) m = fmaxf(m, pwmax[w][t]);
        m = fmaxf(m, 1e-7f);
        wscl[t] = 127.0f / m;
        dscale[f0 + t] = 3.0f * m / 16129.0f;   // 1/(a_scale*w_scale)
    }
    __syncthreads();

    const float ws = wscl[fl];
    {
        uint2 pk;
        pk.x = pack4(v + 0, ws);
        pk.y = pack4(v + 4, ws);
        *(uint2*)&q_t[fl * LDQ + kc * 8] = pk;
    }
    __syncthreads();

    // writeout: 8 rows x 32 chunks of 16B = 256 chunks; threads 0..255
    if (t < 256) {
        const int r = t >> 5;
        const int c = t & 31;
        *(uint4*)&wT8[(size_t)(f0 + r) * K + c * 16] =
            *(const uint4*)&q_t[r * LDQ + c * 16];
    }
}

// --- Phase 2: int8 MFMA GEMM (exact) + dequant + bias ---
// 2048 blocks x 256 threads (4 waves); BM=64, BN=256, one barrier.
// Exactness: x_q,w_q are ints in [-127,127]; K-sum <= 8.3M < 2^24, so
// i32 accumulation == reference fp32 accumulation bit-for-bit.
// A: int8 tile 64x512 = 32 KB LDS via global_load_lds w=16 (8 DMA/wave);
// linear LDS dest + XOR-swizzled global source chunk (c ^= row&7), same XOR
// on ds_read (rule #21; structure verified r6). 4 blocks/CU (VGPR<=128,
// LDS 4x32=128KB): TLP provides 4-way phase diversity per CU -- stage,
// compute, and store phases of different blocks overlap naturally.
// B: 4 frag loads per gk straight from L2-resident wT8 (256 KB).
// Stores: plain cached (r8 showed nontemporal 64B segments amplify writes
// 156->184 MB; r2 plain stores measured 138 MB).
__global__ __launch_bounds__(256, 4)
void gemm_kernel(const unsigned char* __restrict__ xq,
                 const unsigned char* __restrict__ wT8,
                 const float* __restrict__ dscale,
                 const float* __restrict__ bias,
                 float* __restrict__ out) {
    constexpr int BM = 64;
    __shared__ unsigned char As[BM * K];   // 32768 B

    const int t = threadIdx.x;
    const int lane = t & 63;
    const int wave = t >> 6;               // 0..3
    const int m16 = lane & 15;
    const int quad = lane >> 4;
    const int rowt = blockIdx.x >> 1;      // 64-row tile index
    const int colh = blockIdx.x & 1;       // 256-col half
    const int colbase = colh * 256 + wave * 64;

    // ---- stage: wave w DMAs rows w*16..+16; 1 KB per instr (2 rows) ----
    // lane l: row = r0 + (l>>5), in-row chunk (l&31); source chunk XOR row&7.
    #pragma unroll
    for (int i = 0; i < 8; ++i) {
        const int r0 = wave * 16 + i * 2;
        const int row = r0 + (lane >> 5);
        const unsigned char* src =
            xq + (size_t)(rowt * BM + row) * K + (((lane & 31) ^ (row & 7)) * 16);
        __builtin_amdgcn_global_load_lds(
            (const __attribute__((address_space(1))) unsigned int*)src,
            (__attribute__((address_space(3))) unsigned int*)&As[r0 * K],
            16, 0, 0);
    }

    int4v acc[4][4];
    #pragma unroll
    for (int i = 0; i < 4; ++i)
        #pragma unroll
        for (int j = 0; j < 4; ++j)
            acc[i][j] = (int4v){0, 0, 0, 0};

    // per-lane B fragment base: wT8[(colbase + m16)][quad*16]
    const unsigned char* bp = wT8 + (size_t)(colbase + m16) * K + quad * 16;

    // epilogue constants (before barrier; loads overlap DMA)
    float dsv[4], bvv[4];
    #pragma unroll
    for (int nt = 0; nt < 4; ++nt) {
        int col = colbase + nt * 16 + m16;
        dsv[nt] = dscale[col];
        bvv[nt] = bias[col];
    }

    __syncthreads();   // drains DMA queue

    // ---- compute: 8 k-subtiles (K=64 each), barrier-free ----
    const int cswz = m16 & 7;
    #pragma unroll
    for (int gk = 0; gk < 8; ++gk) {
        int4v bf[4];
        #pragma unroll
        for (int nt = 0; nt < 4; ++nt)
            bf[nt] = *(const int4v*)(bp + (size_t)nt * 16 * K + gk * 64);
        int4v af[4];
        const int c = (gk * 4 + quad) ^ cswz;   // swizzled 16B-chunk index
        #pragma unroll
        for (int mt = 0; mt < 4; ++mt)
            af[mt] = *(const int4v*)&As[(mt * 16 + m16) * K + c * 16];
        #pragma unroll
        for (int nt = 0; nt < 4; ++nt)
            #pragma unroll
            for (int mt = 0; mt < 4; ++mt)
                acc[mt][nt] = __builtin_amdgcn_mfma_i32_16x16x64_i8(
                    af[mt], bf[nt], acc[mt][nt], 0, 0, 0);
    }

    // epilogue: C layout col=lane&15, row=quad*4+reg (shape-determined,
    // dtype-independent on gfx950 -- m121/m128). (float)int32 exact (<2^24).
    #pragma unroll
    for (int nt = 0; nt < 4; ++nt) {
        const int col = colbase + nt * 16 + m16;
        #pragma unroll
        for (int mt = 0; mt < 4; ++mt) {
            const size_t row = (size_t)rowt * BM + mt * 16 + quad * 4;
            #pragma unroll
            for (int r = 0; r < 4; ++r)
                out[(row + r) * F + col] = (float)acc[mt][nt][r] * dsv[nt] + bvv[nt];
        }
    }
}

extern "C" void kernel_launch(void* const* d_in, const int* in_sizes, int n_in,
                              void* d_out, int out_size, void* d_ws, size_t ws_size,
                              hipStream_t stream) {
    const float* x    = (const float*)d_in[0];
    const float* kern = (const float*)d_in[1];
    const float* bias = (const float*)d_in[2];
    float* out = (float*)d_out;

    unsigned char* wT8 = (unsigned char*)d_ws;                        // 256 KB
    float* dscale = (float*)((char*)d_ws + 256 * 1024);               // 2 KB
    unsigned char* xq = (unsigned char*)((char*)d_ws + 256 * 1024 + 4096);
    // xq: 65536*512 int8 = 32 MB workspace

    quant_x_kernel<<<(size_t)N * K / 16 / 256, 256, 0, stream>>>(x, xq);
    quant_w_kernel<<<F / 8, 512, 0, stream>>>(kern, wT8, dscale);
    gemm_kernel<<<(N / 64) * 2, 256, 0, stream>>>(xq, wT8, dscale, bias, out);
}

// Round 11
// 269.804 us; speedup vs baseline: 1.3150x; 1.0971x over previous
//
#include <hip/hip_runtime.h>
#include <stdint.h>

// Problem constants (fixed by reference setup_inputs)
constexpr int N = 65536, K = 512, F = 512;
constexpr float ASCALE = 127.0f / 3.0f;   // activation scale (fixed bound 3.0)

typedef int  int4v  __attribute__((ext_vector_type(4)));   // 4 dwords = 16 int8 / i32x4 acc

// round-half-even then clip to [-127,127] (reference order: round, then clip)
__device__ __forceinline__ int quant_i(float v, float s) {
    float q = rintf(v * s);
    q = fminf(fmaxf(q, -127.0f), 127.0f);
    return (int)q;
}

__device__ __forceinline__ unsigned int pack4(const float* v, float s) {
    unsigned int b0 = (unsigned int)quant_i(v[0], s) & 255u;
    unsigned int b1 = (unsigned int)quant_i(v[1], s) & 255u;
    unsigned int b2 = (unsigned int)quant_i(v[2], s) & 255u;
    unsigned int b3 = (unsigned int)quant_i(v[3], s) & 255u;
    return b0 | (b1 << 8) | (b2 << 16) | (b3 << 24);
}

// --- Phase 1: per-output-channel weight quant -> wT8[f][k] (int8), dscale[f] ---
// 64 blocks x 512 threads; block owns 8 f-cols (r3/r6/r10-verified structure).
__global__ __launch_bounds__(512)
void quant_w_kernel(const float* __restrict__ kern,
                    unsigned char* __restrict__ wT8,
                    float* __restrict__ dscale) {
    constexpr int TF = 8;
    constexpr int LDQ = K + 16;               // 528 B row stride (16B-aligned)
    __shared__ float pwmax[8][TF];
    __shared__ float wscl[TF];
    __shared__ unsigned char q_t[TF * LDQ];   // 8 x 528 int8

    const int t = threadIdx.x;
    const int lane = t & 63;
    const int wave = t >> 6;
    const int fl = t & 7;
    const int kc = t >> 3;          // 0..63
    const int f0 = blockIdx.x * TF;

    float v[8];
    const float* kp = kern + (size_t)(kc * 8) * F + f0 + fl;
    #pragma unroll
    for (int j = 0; j < 8; ++j) v[j] = kp[(size_t)j * F];

    float mx = 0.0f;
    #pragma unroll
    for (int j = 0; j < 8; ++j) mx = fmaxf(mx, fabsf(v[j]));
    #pragma unroll
    for (int d = 8; d < 64; d <<= 1) mx = fmaxf(mx, __shfl_xor(mx, d, 64));
    if (lane < 8) pwmax[wave][fl] = mx;
    __syncthreads();

    if (t < TF) {
        float m = 0.0f;
        #pragma unroll
        for (int w = 0; w < 8; ++w) m = fmaxf(m, pwmax[w][t]);
        m = fmaxf(m, 1e-7f);
        wscl[t] = 127.0f / m;
        dscale[f0 + t] = 3.0f * m / 16129.0f;   // 1/(a_scale*w_scale)
    }
    __syncthreads();

    const float ws = wscl[fl];
    {
        uint2 pk;
        pk.x = pack4(v + 0, ws);
        pk.y = pack4(v + 4, ws);
        *(uint2*)&q_t[fl * LDQ + kc * 8] = pk;
    }
    __syncthreads();

    if (t < 256) {
        const int r = t >> 5;
        const int c = t & 31;
        *(uint4*)&wT8[(size_t)(f0 + r) * K + c * 16] =
            *(const uint4*)&q_t[r * LDQ + c * 16];
    }
}

// --- Phase 2: FUSED quant-x + int8 MFMA GEMM (exact) + dequant + bias ---
// 2048 blocks x 256 threads (4 waves, 4 blocks/CU); BM=64, BN=256, one barrier.
// NEW vs r10: x is read as f32 DIRECTLY (no quant_x kernel, no x_q round-trip:
// -160 MB traffic, one fewer serial launch). Staging quants in-register and
// ds_writes int8 into the SAME verified swizzled LDS layout (write side:
// chunk m -> m^(r&7); read side: (gk*4+quad)^(m16&7) -- r10-verified pair).
// Two staging passes of 16 float4/thread; 4 blocks/CU TLP hides the latency
// (r2/r3's fused-staging failure was the 1-2 block/CU regime).
// Column-half pairing: blocks (2i,2i+1) share one x-tile; m204 bijective
// XCD-chunk swizzle puts the pair on the SAME XCD so the 2nd read L2-hits.
// Exactness: ints in [-127,127], K-sum < 2^24 -> i32 accum == fp32 reference.
__global__ __launch_bounds__(256, 4)
void gemm_kernel(const float* __restrict__ x,
                 const unsigned char* __restrict__ wT8,
                 const float* __restrict__ dscale,
                 const float* __restrict__ bias,
                 float* __restrict__ out) {
    constexpr int BM = 64;
    __shared__ unsigned char As[BM * K];   // 32768 B

    const int t = threadIdx.x;
    const int lane = t & 63;
    const int wave = t >> 6;               // 0..3
    const int m16 = lane & 15;
    const int quad = lane >> 4;

    // m204 bijective XCD-chunk swizzle: nwg=2048, q=256/XCD. Pairs (2i,2i+1)
    // are adjacent in the logical space -> same XCD chunk -> L2-shared x-tile.
    const int g = blockIdx.x;
    const int logical = (g & 7) * 256 + (g >> 3);
    const int rowt = logical >> 1;         // 64-row tile index
    const int colh = logical & 1;          // 256-col half
    const int colbase = colh * 256 + wave * 64;

    // ---- fused stage: thread t -> row r=t>>2, sub s=t&3 ----
    // load f32 in 64B lane-bursts (4 lanes cover 64B contiguous), quant,
    // ds_write_b32 at swizzled chunk (m ^ (r&7)), byte s*4 within chunk.
    {
        const int r = t >> 2;
        const int s = t & 3;
        const float* xrow = x + (size_t)(rowt * BM + r) * K + s * 4;
        const int swzbase = r * K;
        #pragma unroll
        for (int p = 0; p < 2; ++p) {
            float4 xv[16];
            #pragma unroll
            for (int j = 0; j < 16; ++j)
                xv[j] = *(const float4*)(xrow + (p * 16 + j) * 16);
            #pragma unroll
            for (int j = 0; j < 16; ++j) {
                const int m = p * 16 + j;
                *(unsigned int*)&As[swzbase + ((m ^ (r & 7)) << 4) + s * 4] =
                    pack4((const float*)&xv[j], ASCALE);
            }
        }
    }

    int4v acc[4][4];
    #pragma unroll
    for (int i = 0; i < 4; ++i)
        #pragma unroll
        for (int j = 0; j < 4; ++j)
            acc[i][j] = (int4v){0, 0, 0, 0};

    // per-lane B fragment base: wT8[(colbase + m16)][quad*16]
    const unsigned char* bp = wT8 + (size_t)(colbase + m16) * K + quad * 16;

    // epilogue constants (loads overlap staging writes)
    float dsv[4], bvv[4];
    #pragma unroll
    for (int nt = 0; nt < 4; ++nt) {
        int col = colbase + nt * 16 + m16;
        dsv[nt] = dscale[col];
        bvv[nt] = bias[col];
    }

    __syncthreads();

    // ---- compute: 8 k-subtiles (K=64 each), barrier-free ----
    const int cswz = m16 & 7;
    #pragma unroll
    for (int gk = 0; gk < 8; ++gk) {
        int4v bf[4];
        #pragma unroll
        for (int nt = 0; nt < 4; ++nt)
            bf[nt] = *(const int4v*)(bp + (size_t)nt * 16 * K + gk * 64);
        int4v af[4];
        const int c = (gk * 4 + quad) ^ cswz;   // swizzled 16B-chunk index
        #pragma unroll
        for (int mt = 0; mt < 4; ++mt)
            af[mt] = *(const int4v*)&As[(mt * 16 + m16) * K + c * 16];
        #pragma unroll
        for (int nt = 0; nt < 4; ++nt)
            #pragma unroll
            for (int mt = 0; mt < 4; ++mt)
                acc[mt][nt] = __builtin_amdgcn_mfma_i32_16x16x64_i8(
                    af[mt], bf[nt], acc[mt][nt], 0, 0, 0);
    }

    // epilogue: C layout col=lane&15, row=quad*4+reg (shape-determined,
    // dtype-independent -- m121/m128; r10-verified). Plain cached stores.
    #pragma unroll
    for (int nt = 0; nt < 4; ++nt) {
        const int col = colbase + nt * 16 + m16;
        #pragma unroll
        for (int mt = 0; mt < 4; ++mt) {
            const size_t row = (size_t)rowt * BM + mt * 16 + quad * 4;
            #pragma unroll
            for (int r = 0; r < 4; ++r)
                out[(row + r) * F + col] = (float)acc[mt][nt][r] * dsv[nt] + bvv[nt];
        }
    }
}

extern "C" void kernel_launch(void* const* d_in, const int* in_sizes, int n_in,
                              void* d_out, int out_size, void* d_ws, size_t ws_size,
                              hipStream_t stream) {
    const float* x    = (const float*)d_in[0];
    const float* kern = (const float*)d_in[1];
    const float* bias = (const float*)d_in[2];
    float* out = (float*)d_out;

    unsigned char* wT8 = (unsigned char*)d_ws;                        // 256 KB
    float* dscale = (float*)((char*)d_ws + 256 * 1024);               // 2 KB

    quant_w_kernel<<<F / 8, 512, 0, stream>>>(kern, wT8, dscale);
    gemm_kernel<<<(N / 64) * 2, 256, 0, stream>>>(x, wT8, dscale, bias, out);
}

// Round 12
// 265.906 us; speedup vs baseline: 1.3343x; 1.0147x over previous
//
#include <hip/hip_runtime.h>
#include <stdint.h>

// Problem constants (fixed by reference setup_inputs)
constexpr int N = 65536, K = 512, F = 512;
constexpr float ASCALE = 127.0f / 3.0f;   // activation scale (fixed bound 3.0)

typedef int  int4v  __attribute__((ext_vector_type(4)));   // 4 dwords = 16 int8 / i32x4 acc

// round-half-even then clip to [-127,127] (reference order: round, then clip)
__device__ __forceinline__ int quant_i(float v, float s) {
    float q = rintf(v * s);
    q = fminf(fmaxf(q, -127.0f), 127.0f);
    return (int)q;
}

__device__ __forceinline__ unsigned int pack4(const float* v, float s) {
    unsigned int b0 = (unsigned int)quant_i(v[0], s) & 255u;
    unsigned int b1 = (unsigned int)quant_i(v[1], s) & 255u;
    unsigned int b2 = (unsigned int)quant_i(v[2], s) & 255u;
    unsigned int b3 = (unsigned int)quant_i(v[3], s) & 255u;
    return b0 | (b1 << 8) | (b2 << 16) | (b3 << 24);
}

// --- Phase 1: per-output-channel weight quant -> wT8[f][k] (int8), dscale[f] ---
// 64 blocks x 512 threads; block owns 8 f-cols (r3/r6/r10/r11-verified).
__global__ __launch_bounds__(512)
void quant_w_kernel(const float* __restrict__ kern,
                    unsigned char* __restrict__ wT8,
                    float* __restrict__ dscale) {
    constexpr int TF = 8;
    constexpr int LDQ = K + 16;               // 528 B row stride (16B-aligned)
    __shared__ float pwmax[8][TF];
    __shared__ float wscl[TF];
    __shared__ unsigned char q_t[TF * LDQ];   // 8 x 528 int8

    const int t = threadIdx.x;
    const int lane = t & 63;
    const int wave = t >> 6;
    const int fl = t & 7;
    const int kc = t >> 3;          // 0..63
    const int f0 = blockIdx.x * TF;

    float v[8];
    const float* kp = kern + (size_t)(kc * 8) * F + f0 + fl;
    #pragma unroll
    for (int j = 0; j < 8; ++j) v[j] = kp[(size_t)j * F];

    float mx = 0.0f;
    #pragma unroll
    for (int j = 0; j < 8; ++j) mx = fmaxf(mx, fabsf(v[j]));
    #pragma unroll
    for (int d = 8; d < 64; d <<= 1) mx = fmaxf(mx, __shfl_xor(mx, d, 64));
    if (lane < 8) pwmax[wave][fl] = mx;
    __syncthreads();

    if (t < TF) {
        float m = 0.0f;
        #pragma unroll
        for (int w = 0; w < 8; ++w) m = fmaxf(m, pwmax[w][t]);
        m = fmaxf(m, 1e-7f);
        wscl[t] = 127.0f / m;
        dscale[f0 + t] = 3.0f * m / 16129.0f;   // 1/(a_scale*w_scale)
    }
    __syncthreads();

    const float ws = wscl[fl];
    {
        uint2 pk;
        pk.x = pack4(v + 0, ws);
        pk.y = pack4(v + 4, ws);
        *(uint2*)&q_t[fl * LDQ + kc * 8] = pk;
    }
    __syncthreads();

    if (t < 256) {
        const int r = t >> 5;
        const int c = t & 31;
        *(uint4*)&wT8[(size_t)(f0 + r) * K + c * 16] =
            *(const uint4*)&q_t[r * LDQ + c * 16];
    }
}

// --- Phase 2: FUSED quant-x + int8 MFMA GEMM (exact) + dequant + bias ---
// 1024 blocks x 512 threads (8 waves, 2 blocks/CU = 16 waves/CU); BM=64,
// BN=F=512 (each x-tile read ONCE -- r11's BN=256 pairing doubled the
// cache-side x traffic), one barrier.
// r11 diagnosis: VGPR_Count=64 forced the compiler to serialize the staged
// loads (in-flight bytes collapse -> 2.25 TB/s). Fixes here:
//  * stage = 4 chunks/thread of 4x float4, explicit 2-deep rotation
//    (load chunk c+1 || quant+ds_write_b128 chunk c) -- static indexing,
//    ~8 loads continuously in flight per thread;
//  * B-fragment double-buffer (prefetch gk+1 during gk MFMAs);
//  * dscale/bias loads moved to epilogue; peak regs ~124 <= 128.
// Quant/swizzle/compute core identical to r10/r11 (absmax-verified):
// write chunk m at m^(r&7); read chunk (gk*4+quad)^(m16&7).
// Exactness: ints in [-127,127], K-sum < 2^24 -> i32 accum == fp32 ref.
__global__ __launch_bounds__(512, 4)
void gemm_kernel(const float* __restrict__ x,
                 const unsigned char* __restrict__ wT8,
                 const float* __restrict__ dscale,
                 const float* __restrict__ bias,
                 float* __restrict__ out) {
    constexpr int BM = 64;
    __shared__ unsigned char As[BM * K];   // 32768 B

    const int t = threadIdx.x;
    const int lane = t & 63;
    const int wave = t >> 6;               // 0..7
    const int m16 = lane & 15;
    const int quad = lane >> 4;

    // XCD swizzle (1024 % 8 == 0 -> simple m157 form is bijective)
    const int g = blockIdx.x;
    const int rowt = (g & 7) * 128 + (g >> 3);   // 64-row tile index
    const int colbase = wave * 64;

    // ---- fused stage: thread t -> row r=t>>3, slot s=t&7; chunks m=s+8c ----
    // chunk m = 16 int8 k-values = 4 float4 of x; one ds_write_b128 each.
    {
        const int r = t >> 3;
        const int s = t & 7;
        const float* xrow = x + (size_t)(rowt * BM + r) * K;
        const int lbase = r * K;
        const int rx = r & 7;
        float4 xa[4], xb[4];
        uint4 pk;

        #pragma unroll
        for (int j = 0; j < 4; ++j) xa[j] = *(const float4*)(xrow + (s + 0) * 16 + j * 4);
        #pragma unroll
        for (int j = 0; j < 4; ++j) xb[j] = *(const float4*)(xrow + (s + 8) * 16 + j * 4);

        // chunk 0 (xa) ; load chunk 2 -> xa
        pk.x = pack4((const float*)&xa[0], ASCALE);
        pk.y = pack4((const float*)&xa[1], ASCALE);
        pk.z = pack4((const float*)&xa[2], ASCALE);
        pk.w = pack4((const float*)&xa[3], ASCALE);
        *(uint4*)&As[lbase + (((s + 0) ^ rx) << 4)] = pk;
        #pragma unroll
        for (int j = 0; j < 4; ++j) xa[j] = *(const float4*)(xrow + (s + 16) * 16 + j * 4);

        // chunk 1 (xb) ; load chunk 3 -> xb
        pk.x = pack4((const float*)&xb[0], ASCALE);
        pk.y = pack4((const float*)&xb[1], ASCALE);
        pk.z = pack4((const float*)&xb[2], ASCALE);
        pk.w = pack4((const float*)&xb[3], ASCALE);
        *(uint4*)&As[lbase + (((s + 8) ^ rx) << 4)] = pk;
        #pragma unroll
        for (int j = 0; j < 4; ++j) xb[j] = *(const float4*)(xrow + (s + 24) * 16 + j * 4);

        // chunk 2 (xa)
        pk.x = pack4((const float*)&xa[0], ASCALE);
        pk.y = pack4((const float*)&xa[1], ASCALE);
        pk.z = pack4((const float*)&xa[2], ASCALE);
        pk.w = pack4((const float*)&xa[3], ASCALE);
        *(uint4*)&As[lbase + (((s + 16) ^ rx) << 4)] = pk;

        // chunk 3 (xb)
        pk.x = pack4((const float*)&xb[0], ASCALE);
        pk.y = pack4((const float*)&xb[1], ASCALE);
        pk.z = pack4((const float*)&xb[2], ASCALE);
        pk.w = pack4((const float*)&xb[3], ASCALE);
        *(uint4*)&As[lbase + (((s + 24) ^ rx) << 4)] = pk;
    }

    // per-lane B fragment base: wT8[(colbase + m16)][quad*16]
    const unsigned char* bp = wT8 + (size_t)(colbase + m16) * K + quad * 16;

    // B(0) loads hoisted pre-barrier (overlap staging VALU)
    int4v bcur[4], bnxt[4];
    #pragma unroll
    for (int nt = 0; nt < 4; ++nt)
        bcur[nt] = *(const int4v*)(bp + (size_t)nt * 16 * K);

    int4v acc[4][4];
    #pragma unroll
    for (int i = 0; i < 4; ++i)
        #pragma unroll
        for (int j = 0; j < 4; ++j)
            acc[i][j] = (int4v){0, 0, 0, 0};

    __syncthreads();

    // ---- compute: 8 k-subtiles (K=64 each), B double-buffered ----
    const int cswz = m16 & 7;
    #pragma unroll
    for (int gk = 0; gk < 8; ++gk) {
        if (gk < 7) {
            #pragma unroll
            for (int nt = 0; nt < 4; ++nt)
                bnxt[nt] = *(const int4v*)(bp + (size_t)nt * 16 * K + (gk + 1) * 64);
        }
        int4v af[4];
        const int c = (gk * 4 + quad) ^ cswz;   // swizzled 16B-chunk index
        #pragma unroll
        for (int mt = 0; mt < 4; ++mt)
            af[mt] = *(const int4v*)&As[(mt * 16 + m16) * K + c * 16];
        #pragma unroll
        for (int nt = 0; nt < 4; ++nt)
            #pragma unroll
            for (int mt = 0; mt < 4; ++mt)
                acc[mt][nt] = __builtin_amdgcn_mfma_i32_16x16x64_i8(
                    af[mt], bcur[nt], acc[mt][nt], 0, 0, 0);
        if (gk < 7) {
            #pragma unroll
            for (int nt = 0; nt < 4; ++nt) bcur[nt] = bnxt[nt];
        }
    }

    // epilogue: C layout col=lane&15, row=quad*4+reg (r10/r11-verified).
    // dscale/bias loaded here (once) to keep main-loop register peak <= 128.
    #pragma unroll
    for (int nt = 0; nt < 4; ++nt) {
        const int col = colbase + nt * 16 + m16;
        const float ds = dscale[col];
        const float bv = bias[col];
        #pragma unroll
        for (int mt = 0; mt < 4; ++mt) {
            const size_t row = (size_t)rowt * BM + mt * 16 + quad * 4;
            #pragma unroll
            for (int r = 0; r < 4; ++r)
                out[(row + r) * F + col] = (float)acc[mt][nt][r] * ds + bv;
        }
    }
}

extern "C" void kernel_launch(void* const* d_in, const int* in_sizes, int n_in,
                              void* d_out, int out_size, void* d_ws, size_t ws_size,
                              hipStream_t stream) {
    const float* x    = (const float*)d_in[0];
    const float* kern = (const float*)d_in[1];
    const float* bias = (const float*)d_in[2];
    float* out = (float*)d_out;

    unsigned char* wT8 = (unsigned char*)d_ws;                        // 256 KB
    float* dscale = (float*)((char*)d_ws + 256 * 1024);               // 2 KB

    quant_w_kernel<<<F / 8, 512, 0, stream>>>(kern, wT8, dscale);
    gemm_kernel<<<N / 64, 512, 0, stream>>>(x, wT8, dscale, bias, out);
}